// Round 1
// baseline (744.828 us; speedup 1.0000x reference)
//
#include <hip/hip_runtime.h>
#include <hip/hip_bf16.h>

#define BATCH 524288LL
#define DIM 128

typedef __attribute__((ext_vector_type(8))) short short8;
typedef __attribute__((ext_vector_type(4))) float f32x4;

__device__ __forceinline__ unsigned short f2bf(float f) {
  unsigned int u = __float_as_uint(f);
  unsigned int r = (u + 0x7fffu + ((u >> 16) & 1u)) >> 16;
  return (unsigned short)r;
}

__device__ __forceinline__ float softplusf(float x) {
  return (x > 20.f) ? x : log1pf(expf(x));
}

// Blocks 0..127: transpose+convert W into wt[n][k] = bf16(w_mu[k][n]).
// Block 128: softplus vectors + KL scalar.
__global__ void setup_kernel(const float* __restrict__ w_mu,
                             const float* __restrict__ w_sigma,
                             const float* __restrict__ b_sigma,
                             unsigned short* __restrict__ wt,
                             float* __restrict__ spw,
                             float* __restrict__ spb,
                             float* __restrict__ kl_out) {
  const int t = threadIdx.x;
  if (blockIdx.x < 128) {
    const int n = blockIdx.x;
    wt[n * 128 + t] = f2bf(w_mu[t * 128 + n]);
    return;
  }
  __shared__ float red[128];
  __shared__ float s_sumabs;
  float swv = softplusf(w_sigma[t]);
  spw[t] = swv;
  spb[t] = softplusf(b_sigma[t]);
  // term2 = sum |w_mu| : thread t sums column t (coalesced across threads)
  float s = 0.f;
  for (int j = 0; j < 128; ++j) s += fabsf(w_mu[j * 128 + t]);
  red[t] = s;
  __syncthreads();
  for (int off = 64; off > 0; off >>= 1) {
    if (t < off) red[t] += red[t + off];
    __syncthreads();
  }
  if (t == 0) s_sumabs = red[0];
  __syncthreads();
  red[t] = logf(swv) - swv;
  __syncthreads();
  for (int off = 64; off > 0; off >>= 1) {
    if (t < off) red[t] += red[t + off];
    __syncthreads();
  }
  // kl = -0.5 * ( sum_j(log spw_j - spw_j) - sum|w_mu| )
  if (t == 0) kl_out[0] = -0.5f * (red[0] - s_sumabs);
}

// Main: 256 threads = 4 waves; each wave computes 32 rows x 128 cols.
// A (x) loaded straight from global, converted to bf16 in-register.
// B (wt) fragments re-read from global each K-step (32 KB, L1/L2-resident).
// quad = sum_i x_i^2 * spw_i accumulated alongside, shfl-redistributed.
__global__ __launch_bounds__(256) void rvlin_main(
    const float* __restrict__ x,
    const unsigned short* __restrict__ wt,
    const float* __restrict__ spw,
    const float* __restrict__ spb,
    const float* __restrict__ bmu,
    float* __restrict__ out) {
  const int tid = threadIdx.x;
  const int wv = tid >> 6;
  const int lane = tid & 63;
  const int rr = lane & 15;   // A row / B col / C col within fragment
  const int kg = lane >> 4;   // k-group 0..3 (8 contiguous k each)
  const long long rbase = (long long)blockIdx.x * 128 + wv * 32;

  f32x4 acc[2][8];
#pragma unroll
  for (int m = 0; m < 2; ++m)
#pragma unroll
    for (int n = 0; n < 8; ++n)
      acc[m][n] = (f32x4){0.f, 0.f, 0.f, 0.f};

  float q0 = 0.f, q1 = 0.f;

  const float* xr0 = x + (rbase + rr) * 128;
  const float* xr1 = xr0 + 16 * 128;

#pragma unroll
  for (int kb = 0; kb < 4; ++kb) {
    const int k0 = kb * 32 + kg * 8;
    const f32x4 sw0 = *(const f32x4*)(spw + k0);
    const f32x4 sw1 = *(const f32x4*)(spw + k0 + 4);
    short8 bfr[8];
#pragma unroll
    for (int n = 0; n < 8; ++n)
      bfr[n] = *(const short8*)(wt + (n * 16 + rr) * 128 + k0);
#pragma unroll
    for (int m = 0; m < 2; ++m) {
      const float* xr = m ? xr1 : xr0;
      const f32x4 xa = *(const f32x4*)(xr + k0);
      const f32x4 xb = *(const f32x4*)(xr + k0 + 4);
      short8 a;
      a[0] = (short)f2bf(xa.x); a[1] = (short)f2bf(xa.y);
      a[2] = (short)f2bf(xa.z); a[3] = (short)f2bf(xa.w);
      a[4] = (short)f2bf(xb.x); a[5] = (short)f2bf(xb.y);
      a[6] = (short)f2bf(xb.z); a[7] = (short)f2bf(xb.w);
      const float qq =
          xa.x * xa.x * sw0.x + xa.y * xa.y * sw0.y +
          xa.z * xa.z * sw0.z + xa.w * xa.w * sw0.w +
          xb.x * xb.x * sw1.x + xb.y * xb.y * sw1.y +
          xb.z * xb.z * sw1.z + xb.w * xb.w * sw1.w;
      if (m == 0) q0 += qq; else q1 += qq;
#pragma unroll
      for (int n = 0; n < 8; ++n)
        acc[m][n] = __builtin_amdgcn_mfma_f32_16x16x32_bf16(a, bfr[n], acc[m][n], 0, 0, 0);
    }
  }

  // quad: full row-sum lives split across the 4 k-groups (same rr) -> butterfly
  q0 += __shfl_xor(q0, 16); q0 += __shfl_xor(q0, 32);
  q1 += __shfl_xor(q1, 16); q1 += __shfl_xor(q1, 32);

  // C/D layout: col = lane&15, row = (lane>>4)*4 + reg. Fetch quad for those rows.
  const int crow = (lane >> 4) * 4;
  float qc0[4], qc1[4];
#pragma unroll
  for (int r = 0; r < 4; ++r) {
    qc0[r] = __shfl(q0, crow + r);
    qc1[r] = __shfl(q1, crow + r);
  }

  float bm[8], sb[8];
#pragma unroll
  for (int n = 0; n < 8; ++n) {
    bm[n] = bmu[n * 16 + rr];
    sb[n] = spb[n * 16 + rr];
  }

  float* out_mu = out;
  float* out_sig = out + BATCH * 128;

#pragma unroll
  for (int m = 0; m < 2; ++m) {
#pragma unroll
    for (int n = 0; n < 8; ++n) {
      const int col = n * 16 + rr;
#pragma unroll
      for (int r = 0; r < 4; ++r) {
        const long long row = rbase + m * 16 + crow + r;
        out_mu[row * 128 + col] = acc[m][n][r] + bm[n];
        out_sig[row * 128 + col] = (m == 0 ? qc0[r] : qc1[r]) + sb[n];
      }
    }
  }
}

extern "C" void kernel_launch(void* const* d_in, const int* in_sizes, int n_in,
                              void* d_out, int out_size, void* d_ws, size_t ws_size,
                              hipStream_t stream) {
  const float* x       = (const float*)d_in[0];
  const float* w_mu    = (const float*)d_in[1];
  const float* w_sigma = (const float*)d_in[2];
  const float* b_mu    = (const float*)d_in[3];
  const float* b_sigma = (const float*)d_in[4];
  float* out = (float*)d_out;

  unsigned short* wt = (unsigned short*)d_ws;                   // 32 KB
  float* spw = (float*)((char*)d_ws + 32768);                   // 512 B
  float* spb = (float*)((char*)d_ws + 32768 + 512);             // 512 B
  float* kl_out = out + 2 * BATCH * 128;                        // scalar slot

  hipLaunchKernelGGL(setup_kernel, dim3(129), dim3(128), 0, stream,
                     w_mu, w_sigma, b_sigma, wt, spw, spb, kl_out);
  hipLaunchKernelGGL(rvlin_main, dim3((unsigned)(BATCH / 128)), dim3(256), 0, stream,
                     x, wt, spw, spb, b_mu, out);
}